// Round 14
// baseline (289.650 us; speedup 1.0000x reference)
//
#include <hip/hip_runtime.h>
#include <hip/hip_bf16.h>

// ---------------------------------------------------------------------------
// CrossDecoderLayer forward. Externals f32. R22: 8-dispatch pipeline:
// [transpose|LN|LN] -> [QKV|KV] -> self_attn -> WO -> [LN+CQ fused] ->
// cross_attn -> [LN2+FF1 fused] -> FF2.
// R22 = R21 (best, 246.2us) + block-local LN fusion: both standalone LN
// kernels feed GEMMs with K=512 = full row, so each consumer GEMM block
// recomputes LN for its own 128 rows (phase 0), writes tn/y/text2 to global
// (8 col-tile blocks write IDENTICAL values = benign race; same-XCD under
// chunked swizzle so re-reads are L2 hits), drains vmcnt + syncthreads,
// then runs the unchanged K-loop reading its own rows via gload_lds.
// Cuts 2 dispatch boundaries + 2 small-kernel launches (R17 showed
// grid.sync is NOT the tool; this needs no cross-block sync).
// GEMM core/self-attn/cross-attn v5 identical to R21.
// B=16, W=256, S=16, V=32, D=512, H=8, Dk=64, DF=1024.
// ---------------------------------------------------------------------------

#define D_MODEL 512
#define NUM_HEAD 8
#define SCALE 0.125f
#define EPS 1e-5f

typedef __hip_bfloat16 bf16;
typedef __attribute__((ext_vector_type(8))) short short8;
typedef __attribute__((ext_vector_type(4))) float floatx4;

static __device__ __forceinline__ float s2f(short u) {
    unsigned int x = ((unsigned int)(unsigned short)u) << 16;
    float f; __builtin_memcpy(&f, &x, 4); return f;
}
static __device__ __forceinline__ short f2s(float f) {
    bf16 t = __float2bfloat16(f);
    short s; __builtin_memcpy(&s, &t, 2); return s;
}

// Direct global->LDS DMA, 16B per lane. dst must be wave-uniform; HW places
// lane i at dst + i*16. src is per-lane.
static __device__ __forceinline__ void gload16(const short* g, short* l) {
    __builtin_amdgcn_global_load_lds(
        (const __attribute__((address_space(1))) unsigned int*)g,
        (__attribute__((address_space(3))) unsigned int*)l, 16, 0, 0);
}

// ---------------- weight transpose args ----------------
struct TransArgs {
    const float* src[9];
    bf16* dst[9];
    int K[9], N[9];
    int start[10];
};

// ------------- wave-parallel LayerNorm row (f32 in -> bf16 out) -------------
// One wave per row: lane l owns elems [l*8, l*8+8). Pure shfl reduce.
static __device__ __forceinline__ void ln_row_wave(const float* __restrict__ inp,
                                                   const float* __restrict__ g,
                                                   const float* __restrict__ bta,
                                                   bf16* __restrict__ out,
                                                   size_t row, int lane) {
    const float* rp = inp + row * D_MODEL + lane * 8;
    const float4 x0 = *(const float4*)rp;
    const float4 x1 = *(const float4*)(rp + 4);
    float s  = x0.x + x0.y + x0.z + x0.w + x1.x + x1.y + x1.z + x1.w;
    float sq = x0.x * x0.x + x0.y * x0.y + x0.z * x0.z + x0.w * x0.w
             + x1.x * x1.x + x1.y * x1.y + x1.z * x1.z + x1.w * x1.w;
    #pragma unroll
    for (int off = 32; off >= 1; off >>= 1) {
        s += __shfl_xor(s, off, 64);
        sq += __shfl_xor(sq, off, 64);
    }
    const float m = s * (1.f / D_MODEL);
    const float var = sq * (1.f / D_MODEL) - m * m;
    const float r = rsqrtf(var + EPS);
    const float4 g0 = *(const float4*)(g + lane * 8);
    const float4 g1 = *(const float4*)(g + lane * 8 + 4);
    const float4 b0 = *(const float4*)(bta + lane * 8);
    const float4 b1 = *(const float4*)(bta + lane * 8 + 4);
    short8 o;
    o[0] = f2s(g0.x * (x0.x - m) * r + b0.x);
    o[1] = f2s(g0.y * (x0.y - m) * r + b0.y);
    o[2] = f2s(g0.z * (x0.z - m) * r + b0.z);
    o[3] = f2s(g0.w * (x0.w - m) * r + b0.w);
    o[4] = f2s(g1.x * (x1.x - m) * r + b1.x);
    o[5] = f2s(g1.y * (x1.y - m) * r + b1.y);
    o[6] = f2s(g1.z * (x1.z - m) * r + b1.z);
    o[7] = f2s(g1.w * (x1.w - m) * r + b1.w);
    *(short8*)((short*)out + row * D_MODEL + lane * 8) = o;
}

// ---- wave-parallel fused dual-LN row: v=LN(a)+LN(c); text2=v f32; y=LN(v) ----
static __device__ __forceinline__ void ln2_row_wave(const float* __restrict__ a,
                                                    const float* __restrict__ c,
                                                    const float* __restrict__ g1,
                                                    const float* __restrict__ b1,
                                                    const float* __restrict__ g2,
                                                    const float* __restrict__ b2,
                                                    const float* __restrict__ g3,
                                                    const float* __restrict__ b3,
                                                    float* __restrict__ text2,
                                                    bf16* __restrict__ y,
                                                    size_t row, int lane) {
    const float* ap = a + row * D_MODEL + lane * 8;
    const float* cp = c + row * D_MODEL + lane * 8;
    const float4 a0 = *(const float4*)ap, a1 = *(const float4*)(ap + 4);
    const float4 c0 = *(const float4*)cp, c1 = *(const float4*)(cp + 4);
    float sa = a0.x + a0.y + a0.z + a0.w + a1.x + a1.y + a1.z + a1.w;
    float qa = a0.x * a0.x + a0.y * a0.y + a0.z * a0.z + a0.w * a0.w
             + a1.x * a1.x + a1.y * a1.y + a1.z * a1.z + a1.w * a1.w;
    float sc = c0.x + c0.y + c0.z + c0.w + c1.x + c1.y + c1.z + c1.w;
    float qc = c0.x * c0.x + c0.y * c0.y + c0.z * c0.z + c0.w * c0.w
             + c1.x * c1.x + c1.y * c1.y + c1.z * c1.z + c1.w * c1.w;
    #pragma unroll
    for (int off = 32; off >= 1; off >>= 1) {
        sa += __shfl_xor(sa, off, 64); qa += __shfl_xor(qa, off, 64);
        sc += __shfl_xor(sc, off, 64); qc += __shfl_xor(qc, off, 64);
    }
    const float ma = sa * (1.f / D_MODEL), mc = sc * (1.f / D_MODEL);
    const float ra = rsqrtf(qa * (1.f / D_MODEL) - ma * ma + EPS);
    const float rc = rsqrtf(qc * (1.f / D_MODEL) - mc * mc + EPS);
    const int e0 = lane * 8;
    float v[8];
    const float av0[8] = {a0.x, a0.y, a0.z, a0.w, a1.x, a1.y, a1.z, a1.w};
    const float cv0[8] = {c0.x, c0.y, c0.z, c0.w, c1.x, c1.y, c1.z, c1.w};
    #pragma unroll
    for (int i = 0; i < 8; i++)
        v[i] = g1[e0 + i] * (av0[i] - ma) * ra + b1[e0 + i]
             + g2[e0 + i] * (cv0[i] - mc) * rc + b2[e0 + i];
    float* tp = text2 + row * D_MODEL + e0;
    *(float4*)tp       = make_float4(v[0], v[1], v[2], v[3]);
    *(float4*)(tp + 4) = make_float4(v[4], v[5], v[6], v[7]);
    float sv = 0.f, qv = 0.f;
    #pragma unroll
    for (int i = 0; i < 8; i++) { sv += v[i]; qv += v[i] * v[i]; }
    #pragma unroll
    for (int off = 32; off >= 1; off >>= 1) {
        sv += __shfl_xor(sv, off, 64); qv += __shfl_xor(qv, off, 64);
    }
    const float mv = sv * (1.f / D_MODEL);
    const float rv = rsqrtf(qv * (1.f / D_MODEL) - mv * mv + EPS);
    short8 o;
    #pragma unroll
    for (int i = 0; i < 8; i++)
        o[i] = f2s(g3[e0 + i] * (v[i] - mv) * rv + b3[e0 + i]);
    *(short8*)((short*)y + row * D_MODEL + e0) = o;
}

// ---- dispatch 1: transpose (blocks [0,nT)) | LN(text) x1024 | LN(av) x2048 ----
__global__ __launch_bounds__(256) void prologue_kernel(TransArgs a, int nT,
                                                       const float* __restrict__ text,
                                                       const float* __restrict__ g1,
                                                       const float* __restrict__ b1,
                                                       bf16* __restrict__ xln,
                                                       const float* __restrict__ av,
                                                       const float* __restrict__ g2,
                                                       const float* __restrict__ b2,
                                                       bf16* __restrict__ an) {
    const int bid = blockIdx.x;
    if (bid >= nT) {
        const int r = bid - nT;
        const int tid = threadIdx.x, lane = tid & 63, w = tid >> 6;
        if (r < 1024) ln_row_wave(text, g1, b1, xln, (size_t)r * 4 + w, lane);
        else          ln_row_wave(av, g2, b2, an, (size_t)(r - 1024) * 4 + w, lane);
        return;
    }
    int m = 0;
    while (bid >= a.start[m + 1]) m++;
    const int t = bid - a.start[m];
    const int N = a.N[m], K = a.K[m];
    const int tilesX = N >> 5;
    const int tx = t % tilesX, ty = t / tilesX;
    __shared__ bf16 tile[32][33];
    const int tid = threadIdx.x;
    const int r = tid >> 3, c0 = (tid & 7) * 4;
    const float* sp = a.src[m] + (size_t)(ty * 32 + r) * N + tx * 32 + c0;
    float4 v = *(const float4*)sp;
    tile[r][c0 + 0] = __float2bfloat16(v.x);
    tile[r][c0 + 1] = __float2bfloat16(v.y);
    tile[r][c0 + 2] = __float2bfloat16(v.z);
    tile[r][c0 + 3] = __float2bfloat16(v.w);
    __syncthreads();
    bf16* dp = a.dst[m] + (size_t)(tx * 32 + r) * K + ty * 32 + c0;
    #pragma unroll
    for (int i = 0; i < 4; i++) dp[i] = tile[c0 + i][r];
}

// ---------------- MFMA GEMM core: dbuf prefetch + gload_lds + XOR swizzle ------
// R12-proven structure. BM=128, BN in {64,128}, BK=64, 4 waves.
// LDS double-buffered, linear [rows][64] per buffer (DMA dest must be linear).
// Swizzle (rule #21): logical (r,c) at LDS shorts r*64 + (c ^ ((r&7)<<3));
// writer pre-swizzles the global source col, reader XORs the k-offset.
// K-loop (T3 minimum): issue t+1's gloads FIRST, compute tile t, then ONE
// __syncthreads() (implicit vmcnt(0) drain lands after the compute).
template <int BN>
static __device__ __forceinline__ void mfma_loop(const short* __restrict__ Ag,
                                                 const short* __restrict__ Bg,
                                                 int m0, int n0, int K,
                                                 short* As, short* Bs,
                                                 floatx4* acc /* [4*(BN/32)] */) {
    constexpr int NI = BN / 32;
    const int tid = threadIdx.x, lane = tid & 63, w = tid >> 6;
    const int quad = lane >> 4, l15 = lane & 15;
    const int wm = (w >> 1) * 64, wn = (w & 1) * (BN / 2);
    const int sr = lane >> 3;
    const int sc = (((lane & 7) ^ sr) & 7) * 8;   // pre-swizzled source col (shorts)
    const int rsw = (l15 & 7) << 3;               // read-side XOR (shorts)

    #define STAGE(buf, kk0)                                                         \
        do {                                                                        \
            short* Ad = As + (buf) * (128 * 64);                                    \
            short* Bd = Bs + (buf) * (BN * 64);                                     \
            _Pragma("unroll")                                                       \
            for (int p = 0; p < 4; p++) {                                           \
                const int rb = w * 32 + p * 8;                                      \
                gload16(&Ag[(size_t)(m0 + rb + sr) * K + (kk0) + sc], &Ad[rb * 64]);\
            }                                                                       \
            _Pragma("unroll")                                                       \
            for (int p = 0; p < BN / 32; p++) {                                     \
                const int rb = w * (BN / 4) + p * 8;                                \
                gload16(&Bg[(size_t)(n0 + rb + sr) * K + (kk0) + sc], &Bd[rb * 64]);\
            }                                                                       \
        } while (0)

    STAGE(0, 0);
    __syncthreads();          // drains vmcnt(0): buf0 ready
    int cur = 0;
    for (int kk0 = 0; kk0 < K; kk0 += 64) {
        const bool more = (kk0 + 64 < K);
        if (more) STAGE(cur ^ 1, kk0 + 64);   // issue next tile's loads first
        const short* Ac = As + cur * (128 * 64);
        const short* Bc = Bs + cur * (BN * 64);
        __builtin_amdgcn_s_setprio(1);
        #pragma unroll
        for (int ks = 0; ks < 2; ks++) {
            const int kc = (ks * 32 + quad * 8) ^ rsw;
            short8 bfr[NI];
            #pragma unroll
            for (int ni = 0; ni < NI; ni++)
                bfr[ni] = *(const short8*)&Bc[(wn + ni * 16 + l15) * 64 + kc];
            #pragma unroll
            for (int mi = 0; mi < 4; mi++) {
                short8 am = *(const short8*)&Ac[(wm + mi * 16 + l15) * 64 + kc];
                #pragma unroll
                for (int ni = 0; ni < NI; ni++)
                    acc[mi * NI + ni] = __builtin_amdgcn_mfma_f32_16x16x32_bf16(
                        am, bfr[ni], acc[mi * NI + ni], 0, 0, 0);
            }
        }
        __builtin_amdgcn_s_setprio(0);
        if (more) __syncthreads();            // drains vmcnt(0): next tile ready
        cur ^= 1;
    }
    #undef STAGE
}

template <int BN, int RES, bool RELU, bool OUT_BF16>
__global__ __launch_bounds__(256) void gemm128(const bf16* __restrict__ A,
                                               const bf16* __restrict__ BT,
                                               const float* __restrict__ bias,
                                               const float* __restrict__ resid,
                                               void* __restrict__ C,
                                               int M, int Ntot, int K) {
    constexpr int NI = BN / 32;
    __shared__ __align__(16) short As[2 * 128 * 64];
    __shared__ __align__(16) short Bs[2 * BN * 64];
    const int nx = gridDim.x;
    const int nwg = nx * gridDim.y;
    int lin = blockIdx.y * nx + blockIdx.x;
    if ((nwg & 7) == 0) lin = (lin & 7) * (nwg >> 3) + (lin >> 3);
    const int m0 = (lin / nx) * 128, n0 = (lin % nx) * BN;
    floatx4 acc[4 * NI] = {};
    mfma_loop<BN>((const short*)A, (const short*)BT, m0, n0, K, As, Bs, acc);
    const int tid = threadIdx.x, lane = tid & 63, w = tid >> 6;
    const int quad = lane >> 4, l15 = lane & 15;
    const int wm = (w >> 1) * 64, wn = (w & 1) * (BN / 2);
    #pragma unroll
    for (int mi = 0; mi < 4; mi++)
        #pragma unroll
        for (int ni = 0; ni < NI; ni++)
            #pragma unroll
            for (int r = 0; r < 4; r++) {
                const int row = m0 + wm + mi * 16 + quad * 4 + r;
                const int col = n0 + wn + ni * 16 + l15;
                float v = acc[mi * NI + ni][r] + bias[col];
                if (RELU) v = fmaxf(v, 0.f);
                if (RES == 1) v += resid[(size_t)row * Ntot + col];
                if (OUT_BF16) ((bf16*)C)[(size_t)row * Ntot + col] = __float2bfloat16(v);
                else          ((float*)C)[(size_t)row * Ntot + col] = v;
            }
}

// ---- fused dispatch 5: LN(text1)->tn (own 128 rows) then CQ gemm (BN=64) ----
// Benign race: the 8 col-tile blocks of a row panel write IDENTICAL tn values.
// vmcnt(0)+syncthreads makes our own stores L2-visible before gload_lds reads.
__global__ __launch_bounds__(256) void fused_ln_cq(const float* __restrict__ text1,
                                                   const float* __restrict__ lng,
                                                   const float* __restrict__ lnb,
                                                   bf16* __restrict__ tn,
                                                   const bf16* __restrict__ cwqT,
                                                   const float* __restrict__ cbq,
                                                   bf16* __restrict__ cqb) {
    __shared__ __align__(16) short As[2 * 128 * 64];
    __shared__ __align__(16) short Bs[2 * 64 * 64];
    const int nx = gridDim.x;
    const int nwg = nx * gridDim.y;
    int lin = blockIdx.y * nx + blockIdx.x;
    if ((nwg & 7) == 0) lin = (lin & 7) * (nwg >> 3) + (lin >> 3);
    const int m0 = (lin / nx) * 128, n0 = (lin % nx) * 64;
    const int tid = threadIdx.x, lane = tid & 63, w = tid >> 6;
    // phase 0: LN rows m0..m0+127 -> tn
    for (int rr = 0; rr < 32; rr++)
        ln_row_wave(text1, lng, lnb, tn, (size_t)m0 + rr * 4 + w, lane);
    asm volatile("s_waitcnt vmcnt(0)" ::: "memory");  // our tn stores in L2
    __syncthreads();
    // phase 1: cqb = tn @ cwqT + cbq (bf16)
    floatx4 acc[8] = {};
    mfma_loop<64>((const short*)tn, (const short*)cwqT, m0, n0, 512, As, Bs, acc);
    const int quad = lane >> 4, l15 = lane & 15;
    const int wm = (w >> 1) * 64, wn = (w & 1) * 32;
    #pragma unroll
    for (int mi = 0; mi < 4; mi++)
        #pragma unroll
        for (int ni = 0; ni < 2; ni++)
            #pragma unroll
            for (int r = 0; r < 4; r++) {
                const int row = m0 + wm + mi * 16 + quad * 4 + r;
                const int col = n0 + wn + ni * 16 + l15;
                cqb[(size_t)row * D_MODEL + col] =
                    __float2bfloat16(acc[mi * 2 + ni][r] + cbq[col]);
            }
}

// ---- fused dispatch 7: LN2(text1,res)->text2,y (own rows) then FF1 (BN=128) ----
__global__ __launch_bounds__(256) void fused_ln2_ff1(const float* __restrict__ text1,
                                                     const float* __restrict__ res,
                                                     const float* __restrict__ g1,
                                                     const float* __restrict__ b1,
                                                     const float* __restrict__ g2,
                                                     const float* __restrict__ b2,
                                                     const float* __restrict__ g3,
                                                     const float* __restrict__ b3,
                                                     float* __restrict__ text2,
                                                     bf16* __restrict__ y,
                                                     const bf16* __restrict__ f1T,
                                                     const float* __restrict__ fb1,
                                                     bf16* __restrict__ h1) {
    __shared__ __align__(16) short As[2 * 128 * 64];
    __shared__ __align__(16) short Bs[2 * 128 * 64];
    const int nx = gridDim.x;
    const int nwg = nx * gridDim.y;
    int lin = blockIdx.y * nx + blockIdx.x;
    if ((nwg & 7) == 0) lin = (lin & 7) * (nwg >> 3) + (lin >> 3);
    const int m0 = (lin / nx) * 128, n0 = (lin % nx) * 128;
    const int tid = threadIdx.x, lane = tid & 63, w = tid >> 6;
    // phase 0: dual-LN rows m0..m0+127 -> text2 (f32), y (bf16)
    for (int rr = 0; rr < 32; rr++)
        ln2_row_wave(text1, res, g1, b1, g2, b2, g3, b3, text2, y,
                     (size_t)m0 + rr * 4 + w, lane);
    asm volatile("s_waitcnt vmcnt(0)" ::: "memory");  // our y stores in L2
    __syncthreads();
    // phase 1: h1 = relu(y @ f1T + fb1) (bf16)
    floatx4 acc[16] = {};
    mfma_loop<128>((const short*)y, (const short*)f1T, m0, n0, 512, As, Bs, acc);
    const int quad = lane >> 4, l15 = lane & 15;
    const int wm = (w >> 1) * 64, wn = (w & 1) * 64;
    #pragma unroll
    for (int mi = 0; mi < 4; mi++)
        #pragma unroll
        for (int ni = 0; ni < 4; ni++)
            #pragma unroll
            for (int r = 0; r < 4; r++) {
                const int row = m0 + wm + mi * 16 + quad * 4 + r;
                const int col = n0 + wn + ni * 16 + l15;
                h1[(size_t)row * 1024 + col] =
                    __float2bfloat16(fmaxf(acc[mi * 4 + ni][r] + fb1[col], 0.f));
            }
}

// ---- dispatch 2: QKV (wid [0,384)) | KV (wid [384,896)), 128x128 tiles ----
__global__ __launch_bounds__(256) void gemm_qkv_kv(const bf16* __restrict__ xln,
                                                   const bf16* __restrict__ wqT,
                                                   const float* __restrict__ bq,
                                                   const float* __restrict__ bk,
                                                   const float* __restrict__ bv,
                                                   bf16* __restrict__ qkv,
                                                   const bf16* __restrict__ an,
                                                   const bf16* __restrict__ cwkT,
                                                   const float* __restrict__ cbk,
                                                   const float* __restrict__ cbv,
                                                   bf16* __restrict__ kvb) {
    __shared__ __align__(16) short As[2 * 128 * 64];
    __shared__ __align__(16) short Bs[2 * 128 * 64];
    // XCD-chunked swizzle over 896 blocks (896/8 = 112, bijective).
    const int bid0 = blockIdx.x;
    const int bid = (bid0 & 7) * 112 + (bid0 >> 3);
    const bf16 *A_, *B_;
    const float *p0, *p1, *p2;
    bf16* Cg;
    int Ntot, m0, n0;
    if (bid < 384) {
        A_ = xln; B_ = wqT; p0 = bq; p1 = bk; p2 = bv; Cg = qkv;
        Ntot = 1536; m0 = (bid / 12) * 128; n0 = (bid % 12) * 128;
    } else {
        const int r = bid - 384;
        A_ = an; B_ = cwkT; p0 = cbk; p1 = cbv; p2 = cbv; Cg = kvb;
        Ntot = 1024; m0 = (r / 8) * 128; n0 = (r % 8) * 128;
    }
    floatx4 acc[16] = {};
    mfma_loop<128>((const short*)A_, (const short*)B_, m0, n0, 512, As, Bs, acc);
    const int tid = threadIdx.x, lane = tid & 63, w = tid >> 6;
    const int quad = lane >> 4, l15 = lane & 15;
    const int wm = (w >> 1) * 64, wn = (w & 1) * 64;
    const int seg = n0 >> 9;
    const float* bias = (seg == 0) ? p0 : ((seg == 1) ? p1 : p2);
    #pragma unroll
    for (int mi = 0; mi < 4; mi++)
        #pragma unroll
        for (int ni = 0; ni < 4; ni++)
            #pragma unroll
            for (int r = 0; r < 4; r++) {
                const int row = m0 + wm + mi * 16 + quad * 4 + r;
                const int col = n0 + wn + ni * 16 + l15;
                Cg[(size_t)row * Ntot + col] =
                    __float2bfloat16(acc[mi * 4 + ni][r] + bias[col & 511]);
            }
}

// ---------------- MFMA flash self-attention (strided qkv input) ----------------
__global__ __launch_bounds__(256) void self_attn_mfma(const bf16* __restrict__ q,
                                                      const bf16* __restrict__ k,
                                                      const bf16* __restrict__ v,
                                                      int ld,
                                                      bf16* __restrict__ sa) {
    const int qc = blockIdx.x, h = blockIdx.y, b = blockIdx.z;
    const int tid = threadIdx.x, lane = tid & 63, w = tid >> 6;
    const int quad = lane >> 4, l15 = lane & 15;
    __shared__ __align__(16) short Kt[64 * 72];
    __shared__ __align__(16) short VT[64 * 72];
    __shared__ __align__(16) short Ps[4][16 * 72];
    const int qrow = b * 256 + qc * 64 + w * 16 + l15;
    const short* qg = (const short*)q + (size_t)qrow * ld + h * 64;
    short8 qf0 = *(const short8*)&qg[quad * 8];
    short8 qf1 = *(const short8*)&qg[32 + quad * 8];
    floatx4 o[4] = {};
    float den[4] = {};
    for (int kt0 = 0; kt0 < 256; kt0 += 64) {
        __syncthreads();
        {
            const int row = tid >> 2, c0 = (tid & 3) * 16;
            const short* kg = (const short*)k + (size_t)(b * 256 + kt0 + row) * ld + h * 64 + c0;
            *(short8*)&Kt[row * 72 + c0]     = *(const short8*)kg;
            *(short8*)&Kt[row * 72 + c0 + 8] = *(const short8*)(kg + 8);
        }
        {
            const int key = tid & 63, dk0 = (tid >> 6) * 16;
            const short* vg = (const short*)v + (size_t)(b * 256 + kt0 + key) * ld + h * 64 + dk0;
            short8 v0 = *(const short8*)vg;
            short8 v1 = *(const short8*)(vg + 8);
            #pragma unroll
            for (int i = 0; i < 8; i++) VT[(dk0 + i) * 72 + key] = v0[i];
            #pragma unroll
            for (int i = 0; i < 8; i++) VT[(dk0 + 8 + i) * 72 + key] = v1[i];
        }
        __syncthreads();
        floatx4 sacc[4] = {};
        #pragma unroll
        for (int ni = 0; ni < 4; ni++) {
            short8 b0 = *(const short8*)&Kt[(ni * 16 + l15) * 72 + quad * 8];
            short8 b1 = *(const short8*)&Kt[(ni * 16 + l15) * 72 + 32 + quad * 8];
            sacc[ni] = __builtin_amdgcn_mfma_f32_16x16x32_bf16(qf0, b0, sacc[ni], 0, 0, 0);
            sacc[ni] = __builtin_amdgcn_mfma_f32_16x16x32_bf16(qf1, b1, sacc[ni], 0, 0, 0);
        }
        #pragma unroll
        for (int ni = 0; ni < 4; ni++)
            #pragma unroll
            for (int r = 0; r < 4; r++) {
                const float e = __expf(sacc[ni][r] * SCALE);
                den[r] += e;
                Ps[w][(quad * 4 + r) * 72 + ni * 16 + l15] = f2s(e);
            }
        #pragma unroll
        for (int kc = 0; kc < 2; kc++) {
            short8 af = *(const short8*)&Ps[w][l15 * 72 + kc * 32 + quad * 8];
            #pragma unroll
            for (int ni = 0; ni < 4; ni++) {
                short8 bv = *(const short8*)&VT[(ni * 16 + l15) * 72 + kc * 32 + quad * 8];
                o[ni] = __builtin_amdgcn_mfma_f32_16x16x32_bf16(af, bv, o[ni], 0, 0, 0);
            }
        }
    }
    #pragma unroll
    for (int off = 1; off < 16; off <<= 1)
        #pragma unroll
        for (int r = 0; r < 4; r++) den[r] += __shfl_xor(den[r], off, 64);
    float inv[4];
    #pragma unroll
    for (int r = 0; r < 4; r++) inv[r] = 1.f / den[r];
    const int qo = b * 256 + qc * 64 + w * 16 + quad * 4;
    #pragma unroll
    for (int ni = 0; ni < 4; ni++)
        #pragma unroll
        for (int r = 0; r < 4; r++)
            sa[(size_t)(qo + r) * D_MODEL + h * 64 + ni * 16 + l15] =
                __float2bfloat16(o[ni][r] * inv[r]);
}

// -------- cross attention v5: v3 algorithm, 512 threads (8 waves/CU) ---------
__global__ __launch_bounds__(512) void cross_attn5(const bf16* __restrict__ kv,
                                                   const bf16* __restrict__ cq,
                                                   const int* __restrict__ sidx,
                                                   float* __restrict__ res,
                                                   float* __restrict__ out_attn) {
    const int s = blockIdx.x, b = blockIdx.y, t = threadIdx.x;
    __shared__ int wrange[2];
    __shared__ __align__(16) short Ks[32 * 576];
    __shared__ __align__(16) short Vs[32 * 576];
    __shared__ __align__(16) short qs[32 * 576];
    __shared__ float att[32 * 256];
    if (t == 0) { wrange[0] = 256; wrange[1] = 0; }
    __syncthreads();
    const int* sb = sidx + b * 256;
    if (t < 256) {
        const int sv = sb[t];
        if (sv == s) {
            if (t == 0 || sb[t - 1] != s) wrange[0] = t;
            if (t == 255 || sb[t + 1] != s) wrange[1] = t + 1;
        }
    }
    {
        const int tt = t & 255;
        const int v = tt >> 3, hh = tt & 7;
        const short* kg = (const short*)kv + ((size_t)((b * 16 + s) * 32 + v)) * 1024 + hh * 64;
        if (t < 256) {
            short* kd = &Ks[v * 576 + hh * 72];
            #pragma unroll
            for (int c = 0; c < 8; c++)
                *(short8*)&kd[c * 8] = *(const short8*)&kg[c * 8];
        } else {
            const short* vg = kg + 512;
            short* vd = &Vs[v * 576 + hh * 72];
            #pragma unroll
            for (int c = 0; c < 8; c++)
                *(short8*)&vd[c * 8] = *(const short8*)&vg[c * 8];
        }
    }
    __syncthreads();
    const int w0 = wrange[0], w1 = wrange[1];
    const int half = t >> 8, tt = t & 255;
    const int h2 = tt >> 5, dp = tt & 31;
    const short* cqg = (const short*)cq;
    for (int wc = w0; wc < w1; wc += 32) {
        const int len = (w1 - wc < 32) ? (w1 - wc) : 32;
        for (int i = t; i < len * 64; i += 512) {
            const int e = i * 8;
            const int row = e >> 9, col = e & 511;
            *(short8*)&qs[row * 576 + (col >> 6) * 72 + (col & 63)] =
                *(const short8*)&cqg[((size_t)(b * 256 + wc + row)) * 512 + col];
        }
        __syncthreads();
        for (int i = t; i < len * 256; i += 512) {
            const int wl = i >> 8, r = i & 255, v = r >> 3, h = r & 7;
            const short* qp = &qs[wl * 576 + h * 72];
            const short* kp = &Ks[v * 576 + h * 72];
            float dot = 0.f;
            #pragma unroll
            for (int c = 0; c < 8; c++) {
                short8 q8 = *(const short8*)&qp[c * 8];
                short8 k8 = *(const short8*)&kp[c * 8];
                dot += s2f(q8[0]) * s2f(k8[0]) + s2f(q8[1]) * s2f(k8[1])
                     + s2f(q8[2]) * s2f(k8[2]) + s2f(q8[3]) * s2f(k8[3])
                     + s2f(q8[4]) * s2f(k8[4]) + s2f(q8[5]) * s2f(k8[5])
                     + s2f(q8[6]) * s2f(k8[6]) + s2f(q8[7]) * s2f(k8[7]);
            }
            att[wl * 256 + r] = 1.f / (1.f + __expf(-dot * SCALE));
        }
        __syncthreads();
        for (int wl = half; wl < len; wl += 2) {
            float r0 = 0.f, r1 = 0.f;
            #pragma unroll
            for (int vv = 0; vv < 32; ++vv) {
                const float av = att[wl * 256 + vv * 8 + h2];
                const int pv = *(const int*)&Vs[vv * 576 + h2 * 72 + dp * 2];
                r0 += av * s2f((short)(pv & 0xffff));
                r1 += av * s2f((short)(pv >> 16));
            }
            *(float2*)&res[((size_t)(b * 256 + wc + wl)) * 512 + h2 * 64 + dp * 2] =
                make_float2(r0, r1);
        }
        if (t < 32) {
            for (int wl = 0; wl < len; wl++) {
                float m = 0.f;
                #pragma unroll
                for (int j = 0; j < 8; j++) m += att[wl * 256 + t * 8 + j];
                out_attn[((size_t)(b * 256 + wc + wl)) * 32 + t] = m * 0.125f;
            }
        }
        __syncthreads();
    }
}

// ---------------------------------------------------------------------------
extern "C" void kernel_launch(void* const* d_in, const int* in_sizes, int n_in,
                              void* d_out, int out_size, void* d_ws, size_t ws_size,
                              hipStream_t stream) {
    const int B = 16, S = 16;
    const int M1 = 4096, M2 = 8192;

    const float* text = (const float*)d_in[0];
    const float* av   = (const float*)d_in[1];
    const int* sidx   = (const int*)d_in[3];
    const float* ln_res1_g = (const float*)d_in[4];
    const float* ln_res1_b = (const float*)d_in[5];
    const float* sa_wq = (const float*)d_in[6];
    const float* sa_bq = (const float*)d_in[7];
    const float* sa_wk = (const float*)d_in[8];
    const float* sa_bk = (const float*)d_in[9];
    const float* sa_wv = (const float*)d_in[10];
    const float* sa_bv = (const float*)d_in[11];
    const float* sa_wo = (const float*)d_in[12];
    const float* sa_bo = (const float*)d_in[13];
    const float* ca_ln_text_g = (const float*)d_in[14];
    const float* ca_ln_text_b = (const float*)d_in[15];
    const float* ca_ln_av_g = (const float*)d_in[16];
    const float* ca_ln_av_b = (const float*)d_in[17];
    const float* ca_wq = (const float*)d_in[18];
    const float* ca_bq = (const float*)d_in[19];
    const float* ca_wk = (const float*)d_in[20];
    const float* ca_bk = (const float*)d_in[21];
    const float* ca_wv = (const float*)d_in[22];
    const float* ca_bv = (const float*)d_in[23];
    const float* ln1_g = (const float*)d_in[24];
    const float* ln1_b = (const float*)d_in[25];
    const float* ln2_g = (const float*)d_in[26];
    const float* ln2_b = (const float*)d_in[27];
    const float* ln_res2_g = (const float*)d_in[28];
    const float* ln_res2_b = (const float*)d_in[29];
    const float* ff_w1 = (const float*)d_in[30];
    const float* ff_b1 = (const float*)d_in[31];
    const float* ff_w2 = (const float*)d_in[32];
    const float* ff_b2 = (const float*)d_in[33];

    // ---- workspace arena (byte offsets; all unique, 94 MB total) ----
    char* wsb = (char*)d_ws;
    const size_t MBy = 1024 * 1024;
    bf16*  WT    = (bf16*)(wsb);               // 0-6 weightsT
    bf16*  xln   = (bf16*)(wsb + 6 * MBy);     // 6-10 [4096][512]
    bf16*  qkv   = (bf16*)(wsb + 10 * MBy);    // 10-22 [4096][1536]
    bf16*  sab   = (bf16*)(wsb + 22 * MBy);    // 22-26
    float* text1 = (float*)(wsb + 26 * MBy);   // 26-34 f32
    bf16*  tn    = (bf16*)(wsb + 34 * MBy);    // 34-38
    bf16*  an    = (bf16*)(wsb + 38 * MBy);    // 38-46 [8192][512]
    bf16*  cqb   = (bf16*)(wsb + 46 * MBy);    // 46-50 [4096][512]
    bf16*  kvb   = (bf16*)(wsb + 50 * MBy);    // 50-66 [8192][1024]
    float* res   = (float*)(wsb + 66 * MBy);   // 66-74 f32
    float* text2 = (float*)(wsb + 74 * MBy);   // 74-82 f32
    bf16*  y     = (bf16*)(wsb + 82 * MBy);    // 82-86
    bf16*  h1    = (bf16*)(wsb + 86 * MBy);    // 86-94 [4096][1024]

    bf16* wqT  = WT;                 // wq|wk|wv contiguous => [1536][512]
    bf16* cwqT = WT + 1048576;
    bf16* cwkT = WT + 1310720;       // cwk|cwv contiguous => [1024][512]
    bf16* woT  = WT + 786432;
    bf16* f1T  = WT + 1835008;       // [1024][512]
    bf16* f2T  = WT + 2359296;       // [512][1024]

    float* out_text = (float*)d_out;
    float* out_attn = (float*)d_out + (size_t)M1 * D_MODEL;

    // ---- transpose plan ----
    TransArgs ta;
    const float* srcs[9] = {sa_wq, sa_wk, sa_wv, sa_wo, ca_wq, ca_wk, ca_wv, ff_w1, ff_w2};
    bf16* dsts[9] = {wqT, WT + 262144, WT + 524288, woT, cwqT, cwkT, WT + 1572864, f1T, f2T};
    const int Ks_[9] = {512, 512, 512, 512, 512, 512, 512, 512, 1024};
    const int Ns_[9] = {512, 512, 512, 512, 512, 512, 512, 1024, 512};
    int cum = 0;
    for (int i = 0; i < 9; i++) {
        ta.src[i] = srcs[i]; ta.dst[i] = dsts[i]; ta.K[i] = Ks_[i]; ta.N[i] = Ns_[i];
        ta.start[i] = cum;
        cum += (Ks_[i] >> 5) * (Ns_[i] >> 5);
    }
    ta.start[9] = cum;   // 2816

    const dim3 blk256(256);
    const dim3 gD(8, 32);       // N=512, BN=64 -> 256 blocks
    const dim3 gF1(8, 32);      // N=1024, BN=128 -> 256 blocks

    // 1. prologue: transpose | LN(text) x1024 | LN(av) x2048 (wave-parallel)
    prologue_kernel<<<cum + 1024 + 2048, blk256, 0, stream>>>(ta, cum,
                                                              text, ln_res1_g, ln_res1_b, xln,
                                                              av, ca_ln_av_g, ca_ln_av_b, an);
    // 2. QKV | KV fused projections (one dispatch, 128x128 tiles, 896 blocks)
    gemm_qkv_kv<<<896, blk256, 0, stream>>>(xln, wqT, sa_bq, sa_bk, sa_bv, qkv,
                                            an, cwkT, ca_bk, ca_bv, kvb);
    // 3. MFMA flash self attention (strided qkv) -> sab bf16
    self_attn_mfma<<<dim3(4, NUM_HEAD, B), blk256, 0, stream>>>(qkv, qkv + 512, qkv + 1024, 1536, sab);
    // 4. text1 = text + sab @ woT + bo (f32)
    gemm128<64, 1, false, false><<<gD, blk256, 0, stream>>>(sab, woT, sa_bo, text, text1, M1, D_MODEL, D_MODEL);
    // 5. fused: tn = LN(text1) (block-local rows) -> cqb = tn @ cwqT + cbq
    fused_ln_cq<<<gD, blk256, 0, stream>>>(text1, ca_ln_text_g, ca_ln_text_b, tn,
                                           cwqT, ca_bq, cqb);
    // 6. cross attention v5 (bf16 q, 512 threads; fuses att-mean -> out_attn)
    cross_attn5<<<dim3(S, B), dim3(512), 0, stream>>>(kvb, cqb, sidx, res, out_attn);
    // 7. fused: text2/y = LN2(text1,res) (block-local rows) -> h1 = relu(y@f1T+b1)
    fused_ln2_ff1<<<gF1, blk256, 0, stream>>>(text1, res, ln1_g, ln1_b, ln2_g, ln2_b,
                                              ln_res2_g, ln_res2_b, text2, y,
                                              f1T, ff_b1, h1);
    // 8. out = text2 + h1 @ f2T + b2 -> f32 d_out
    gemm128<64, 1, false, false><<<gD, blk256, 0, stream>>>(h1, f2T, ff_b2, text2, out_text, M1, D_MODEL, 1024);
}

// Round 15
// 246.201 us; speedup vs baseline: 1.1765x; 1.1765x over previous
//
#include <hip/hip_runtime.h>
#include <hip/hip_bf16.h>

// ---------------------------------------------------------------------------
// CrossDecoderLayer forward. Externals f32. 10-dispatch pipeline (R21 graph):
// [transpose|LN(text)|LN(av)] -> [QKV|KV gemm] -> self_attn -> WO -> LN ->
// CQ -> cross_attn -> LN2 -> FF1 -> FF2.
// R23 = R21 (best, 246.2us) + 64x64 transpose tiles in the prologue
// (2816 -> 704 transpose blocks, 16 elems/thread). R22's block-local LN
// fusion REVERTED: 8x duplicated LN traffic (52.8us fused_ln2_ff1) >>
// 2 dispatch boundaries. GEMMs: R12 dbuf + gload_lds + XOR swizzle + XCD
// chunk. LN: wave-per-row. cross-attn v5: 512 threads.
// B=16, W=256, S=16, V=32, D=512, H=8, Dk=64, DF=1024.
// ---------------------------------------------------------------------------

#define D_MODEL 512
#define NUM_HEAD 8
#define SCALE 0.125f
#define EPS 1e-5f

typedef __hip_bfloat16 bf16;
typedef __attribute__((ext_vector_type(8))) short short8;
typedef __attribute__((ext_vector_type(4))) float floatx4;

static __device__ __forceinline__ float s2f(short u) {
    unsigned int x = ((unsigned int)(unsigned short)u) << 16;
    float f; __builtin_memcpy(&f, &x, 4); return f;
}
static __device__ __forceinline__ short f2s(float f) {
    bf16 t = __float2bfloat16(f);
    short s; __builtin_memcpy(&s, &t, 2); return s;
}

// Direct global->LDS DMA, 16B per lane. dst must be wave-uniform; HW places
// lane i at dst + i*16. src is per-lane.
static __device__ __forceinline__ void gload16(const short* g, short* l) {
    __builtin_amdgcn_global_load_lds(
        (const __attribute__((address_space(1))) unsigned int*)g,
        (__attribute__((address_space(3))) unsigned int*)l, 16, 0, 0);
}

// ---------------- weight transpose args ----------------
struct TransArgs {
    const float* src[9];
    bf16* dst[9];
    int K[9], N[9];
    int start[10];
};

// ------------- wave-parallel LayerNorm row (f32 in -> bf16 out) -------------
// One wave per row: lane l owns elems [l*8, l*8+8). Pure shfl reduce.
static __device__ __forceinline__ void ln_row_wave(const float* __restrict__ inp,
                                                   const float* __restrict__ g,
                                                   const float* __restrict__ bta,
                                                   bf16* __restrict__ out,
                                                   size_t row, int lane) {
    const float* rp = inp + row * D_MODEL + lane * 8;
    const float4 x0 = *(const float4*)rp;
    const float4 x1 = *(const float4*)(rp + 4);
    float s  = x0.x + x0.y + x0.z + x0.w + x1.x + x1.y + x1.z + x1.w;
    float sq = x0.x * x0.x + x0.y * x0.y + x0.z * x0.z + x0.w * x0.w
             + x1.x * x1.x + x1.y * x1.y + x1.z * x1.z + x1.w * x1.w;
    #pragma unroll
    for (int off = 32; off >= 1; off >>= 1) {
        s += __shfl_xor(s, off, 64);
        sq += __shfl_xor(sq, off, 64);
    }
    const float m = s * (1.f / D_MODEL);
    const float var = sq * (1.f / D_MODEL) - m * m;
    const float r = rsqrtf(var + EPS);
    const float4 g0 = *(const float4*)(g + lane * 8);
    const float4 g1 = *(const float4*)(g + lane * 8 + 4);
    const float4 b0 = *(const float4*)(bta + lane * 8);
    const float4 b1 = *(const float4*)(bta + lane * 8 + 4);
    short8 o;
    o[0] = f2s(g0.x * (x0.x - m) * r + b0.x);
    o[1] = f2s(g0.y * (x0.y - m) * r + b0.y);
    o[2] = f2s(g0.z * (x0.z - m) * r + b0.z);
    o[3] = f2s(g0.w * (x0.w - m) * r + b0.w);
    o[4] = f2s(g1.x * (x1.x - m) * r + b1.x);
    o[5] = f2s(g1.y * (x1.y - m) * r + b1.y);
    o[6] = f2s(g1.z * (x1.z - m) * r + b1.z);
    o[7] = f2s(g1.w * (x1.w - m) * r + b1.w);
    *(short8*)((short*)out + row * D_MODEL + lane * 8) = o;
}

// 4 rows per block (wave w -> row base+w)
__global__ __launch_bounds__(256) void ln_kernel(const float* __restrict__ inp,
                                                 const float* __restrict__ g,
                                                 const float* __restrict__ bta,
                                                 bf16* __restrict__ out) {
    const int tid = threadIdx.x;
    ln_row_wave(inp, g, bta, out, (size_t)blockIdx.x * 4 + (tid >> 6), tid & 63);
}

// ---- dispatch 1: transpose 64x64 (blocks [0,nT)) | LN(text) | LN(av) ----
__global__ __launch_bounds__(256) void prologue_kernel(TransArgs a, int nT,
                                                       const float* __restrict__ text,
                                                       const float* __restrict__ g1,
                                                       const float* __restrict__ b1,
                                                       bf16* __restrict__ xln,
                                                       const float* __restrict__ av,
                                                       const float* __restrict__ g2,
                                                       const float* __restrict__ b2,
                                                       bf16* __restrict__ an) {
    const int bid = blockIdx.x;
    if (bid >= nT) {
        const int r = bid - nT;
        const int tid = threadIdx.x, lane = tid & 63, w = tid >> 6;
        if (r < 1024) ln_row_wave(text, g1, b1, xln, (size_t)r * 4 + w, lane);
        else          ln_row_wave(av, g2, b2, an, (size_t)(r - 1024) * 4 + w, lane);
        return;
    }
    int m = 0;
    while (bid >= a.start[m + 1]) m++;
    const int t = bid - a.start[m];
    const int N = a.N[m], K = a.K[m];
    const int tilesX = N >> 6;
    const int tx = t % tilesX, ty = t / tilesX;
    __shared__ bf16 tile[64][65];
    const int tid = threadIdx.x;
    const int r = tid >> 2, c0 = (tid & 3) * 16;   // thread: row r, 16 cols
    const float* sp = a.src[m] + (size_t)(ty * 64 + r) * N + tx * 64 + c0;
    #pragma unroll
    for (int j = 0; j < 4; j++) {
        const float4 v = *(const float4*)(sp + j * 4);
        tile[r][c0 + j * 4 + 0] = __float2bfloat16(v.x);
        tile[r][c0 + j * 4 + 1] = __float2bfloat16(v.y);
        tile[r][c0 + j * 4 + 2] = __float2bfloat16(v.z);
        tile[r][c0 + j * 4 + 3] = __float2bfloat16(v.w);
    }
    __syncthreads();
    bf16* dp = a.dst[m] + (size_t)(tx * 64 + r) * K + ty * 64 + c0;
    #pragma unroll
    for (int i = 0; i < 16; i++) dp[i] = tile[c0 + i][r];
}

// --- wave-parallel fused: v = LN(a)+LN(c); text2=v (f32); y=LN(v) bf16 ---
__global__ __launch_bounds__(256) void ln2_add_ln_kernel(const float* __restrict__ a,
                                                         const float* __restrict__ c,
                                                         const float* __restrict__ g1,
                                                         const float* __restrict__ b1,
                                                         const float* __restrict__ g2,
                                                         const float* __restrict__ b2,
                                                         const float* __restrict__ g3,
                                                         const float* __restrict__ b3,
                                                         float* __restrict__ text2,
                                                         bf16* __restrict__ y) {
    const int tid = threadIdx.x, lane = tid & 63;
    const size_t row = (size_t)blockIdx.x * 4 + (tid >> 6);
    const float* ap = a + row * D_MODEL + lane * 8;
    const float* cp = c + row * D_MODEL + lane * 8;
    const float4 a0 = *(const float4*)ap, a1 = *(const float4*)(ap + 4);
    const float4 c0 = *(const float4*)cp, c1 = *(const float4*)(cp + 4);
    float sa = a0.x + a0.y + a0.z + a0.w + a1.x + a1.y + a1.z + a1.w;
    float qa = a0.x * a0.x + a0.y * a0.y + a0.z * a0.z + a0.w * a0.w
             + a1.x * a1.x + a1.y * a1.y + a1.z * a1.z + a1.w * a1.w;
    float sc = c0.x + c0.y + c0.z + c0.w + c1.x + c1.y + c1.z + c1.w;
    float qc = c0.x * c0.x + c0.y * c0.y + c0.z * c0.z + c0.w * c0.w
             + c1.x * c1.x + c1.y * c1.y + c1.z * c1.z + c1.w * c1.w;
    #pragma unroll
    for (int off = 32; off >= 1; off >>= 1) {
        sa += __shfl_xor(sa, off, 64); qa += __shfl_xor(qa, off, 64);
        sc += __shfl_xor(sc, off, 64); qc += __shfl_xor(qc, off, 64);
    }
    const float ma = sa * (1.f / D_MODEL), mc = sc * (1.f / D_MODEL);
    const float ra = rsqrtf(qa * (1.f / D_MODEL) - ma * ma + EPS);
    const float rc = rsqrtf(qc * (1.f / D_MODEL) - mc * mc + EPS);
    const int e0 = lane * 8;
    float v[8];
    const float av0[8] = {a0.x, a0.y, a0.z, a0.w, a1.x, a1.y, a1.z, a1.w};
    const float cv0[8] = {c0.x, c0.y, c0.z, c0.w, c1.x, c1.y, c1.z, c1.w};
    #pragma unroll
    for (int i = 0; i < 8; i++)
        v[i] = g1[e0 + i] * (av0[i] - ma) * ra + b1[e0 + i]
             + g2[e0 + i] * (cv0[i] - mc) * rc + b2[e0 + i];
    float* tp = text2 + row * D_MODEL + e0;
    *(float4*)tp       = make_float4(v[0], v[1], v[2], v[3]);
    *(float4*)(tp + 4) = make_float4(v[4], v[5], v[6], v[7]);
    float sv = 0.f, qv = 0.f;
    #pragma unroll
    for (int i = 0; i < 8; i++) { sv += v[i]; qv += v[i] * v[i]; }
    #pragma unroll
    for (int off = 32; off >= 1; off >>= 1) {
        sv += __shfl_xor(sv, off, 64); qv += __shfl_xor(qv, off, 64);
    }
    const float mv = sv * (1.f / D_MODEL);
    const float rv = rsqrtf(qv * (1.f / D_MODEL) - mv * mv + EPS);
    short8 o;
    #pragma unroll
    for (int i = 0; i < 8; i++)
        o[i] = f2s(g3[e0 + i] * (v[i] - mv) * rv + b3[e0 + i]);
    *(short8*)((short*)y + row * D_MODEL + e0) = o;
}

// ---------------- MFMA GEMM core: dbuf prefetch + gload_lds + XOR swizzle ------
// R12-proven structure. BM=128, BN in {64,128}, BK=64, 4 waves.
// LDS double-buffered, linear [rows][64] per buffer (DMA dest must be linear).
// Swizzle (rule #21): logical (r,c) at LDS shorts r*64 + (c ^ ((r&7)<<3));
// writer pre-swizzles the global source col, reader XORs the k-offset.
// K-loop (T3 minimum): issue t+1's gloads FIRST, compute tile t, then ONE
// __syncthreads() (implicit vmcnt(0) drain lands after the compute).
template <int BN>
static __device__ __forceinline__ void mfma_loop(const short* __restrict__ Ag,
                                                 const short* __restrict__ Bg,
                                                 int m0, int n0, int K,
                                                 short* As, short* Bs,
                                                 floatx4* acc /* [4*(BN/32)] */) {
    constexpr int NI = BN / 32;
    const int tid = threadIdx.x, lane = tid & 63, w = tid >> 6;
    const int quad = lane >> 4, l15 = lane & 15;
    const int wm = (w >> 1) * 64, wn = (w & 1) * (BN / 2);
    const int sr = lane >> 3;
    const int sc = (((lane & 7) ^ sr) & 7) * 8;   // pre-swizzled source col (shorts)
    const int rsw = (l15 & 7) << 3;               // read-side XOR (shorts)

    #define STAGE(buf, kk0)                                                         \
        do {                                                                        \
            short* Ad = As + (buf) * (128 * 64);                                    \
            short* Bd = Bs + (buf) * (BN * 64);                                     \
            _Pragma("unroll")                                                       \
            for (int p = 0; p < 4; p++) {                                           \
                const int rb = w * 32 + p * 8;                                      \
                gload16(&Ag[(size_t)(m0 + rb + sr) * K + (kk0) + sc], &Ad[rb * 64]);\
            }                                                                       \
            _Pragma("unroll")                                                       \
            for (int p = 0; p < BN / 32; p++) {                                     \
                const int rb = w * (BN / 4) + p * 8;                                \
                gload16(&Bg[(size_t)(n0 + rb + sr) * K + (kk0) + sc], &Bd[rb * 64]);\
            }                                                                       \
        } while (0)

    STAGE(0, 0);
    __syncthreads();          // drains vmcnt(0): buf0 ready
    int cur = 0;
    for (int kk0 = 0; kk0 < K; kk0 += 64) {
        const bool more = (kk0 + 64 < K);
        if (more) STAGE(cur ^ 1, kk0 + 64);   // issue next tile's loads first
        const short* Ac = As + cur * (128 * 64);
        const short* Bc = Bs + cur * (BN * 64);
        __builtin_amdgcn_s_setprio(1);
        #pragma unroll
        for (int ks = 0; ks < 2; ks++) {
            const int kc = (ks * 32 + quad * 8) ^ rsw;
            short8 bfr[NI];
            #pragma unroll
            for (int ni = 0; ni < NI; ni++)
                bfr[ni] = *(const short8*)&Bc[(wn + ni * 16 + l15) * 64 + kc];
            #pragma unroll
            for (int mi = 0; mi < 4; mi++) {
                short8 am = *(const short8*)&Ac[(wm + mi * 16 + l15) * 64 + kc];
                #pragma unroll
                for (int ni = 0; ni < NI; ni++)
                    acc[mi * NI + ni] = __builtin_amdgcn_mfma_f32_16x16x32_bf16(
                        am, bfr[ni], acc[mi * NI + ni], 0, 0, 0);
            }
        }
        __builtin_amdgcn_s_setprio(0);
        if (more) __syncthreads();            // drains vmcnt(0): next tile ready
        cur ^= 1;
    }
    #undef STAGE
}

template <int BN, int RES, bool RELU, bool OUT_BF16>
__global__ __launch_bounds__(256) void gemm128(const bf16* __restrict__ A,
                                               const bf16* __restrict__ BT,
                                               const float* __restrict__ bias,
                                               const float* __restrict__ resid,
                                               void* __restrict__ C,
                                               int M, int Ntot, int K) {
    constexpr int NI = BN / 32;
    __shared__ __align__(16) short As[2 * 128 * 64];
    __shared__ __align__(16) short Bs[2 * BN * 64];
    const int nx = gridDim.x;
    const int nwg = nx * gridDim.y;
    int lin = blockIdx.y * nx + blockIdx.x;
    if ((nwg & 7) == 0) lin = (lin & 7) * (nwg >> 3) + (lin >> 3);
    const int m0 = (lin / nx) * 128, n0 = (lin % nx) * BN;
    floatx4 acc[4 * NI] = {};
    mfma_loop<BN>((const short*)A, (const short*)BT, m0, n0, K, As, Bs, acc);
    const int tid = threadIdx.x, lane = tid & 63, w = tid >> 6;
    const int quad = lane >> 4, l15 = lane & 15;
    const int wm = (w >> 1) * 64, wn = (w & 1) * (BN / 2);
    #pragma unroll
    for (int mi = 0; mi < 4; mi++)
        #pragma unroll
        for (int ni = 0; ni < NI; ni++)
            #pragma unroll
            for (int r = 0; r < 4; r++) {
                const int row = m0 + wm + mi * 16 + quad * 4 + r;
                const int col = n0 + wn + ni * 16 + l15;
                float v = acc[mi * NI + ni][r] + bias[col];
                if (RELU) v = fmaxf(v, 0.f);
                if (RES == 1) v += resid[(size_t)row * Ntot + col];
                if (OUT_BF16) ((bf16*)C)[(size_t)row * Ntot + col] = __float2bfloat16(v);
                else          ((float*)C)[(size_t)row * Ntot + col] = v;
            }
}

// ---- dispatch 2: QKV (wid [0,384)) | KV (wid [384,896)), 128x128 tiles ----
__global__ __launch_bounds__(256) void gemm_qkv_kv(const bf16* __restrict__ xln,
                                                   const bf16* __restrict__ wqT,
                                                   const float* __restrict__ bq,
                                                   const float* __restrict__ bk,
                                                   const float* __restrict__ bv,
                                                   bf16* __restrict__ qkv,
                                                   const bf16* __restrict__ an,
                                                   const bf16* __restrict__ cwkT,
                                                   const float* __restrict__ cbk,
                                                   const float* __restrict__ cbv,
                                                   bf16* __restrict__ kvb) {
    __shared__ __align__(16) short As[2 * 128 * 64];
    __shared__ __align__(16) short Bs[2 * 128 * 64];
    // XCD-chunked swizzle over 896 blocks (896/8 = 112, bijective).
    const int bid0 = blockIdx.x;
    const int bid = (bid0 & 7) * 112 + (bid0 >> 3);
    const bf16 *A_, *B_;
    const float *p0, *p1, *p2;
    bf16* Cg;
    int Ntot, m0, n0;
    if (bid < 384) {
        A_ = xln; B_ = wqT; p0 = bq; p1 = bk; p2 = bv; Cg = qkv;
        Ntot = 1536; m0 = (bid / 12) * 128; n0 = (bid % 12) * 128;
    } else {
        const int r = bid - 384;
        A_ = an; B_ = cwkT; p0 = cbk; p1 = cbv; p2 = cbv; Cg = kvb;
        Ntot = 1024; m0 = (r / 8) * 128; n0 = (r % 8) * 128;
    }
    floatx4 acc[16] = {};
    mfma_loop<128>((const short*)A_, (const short*)B_, m0, n0, 512, As, Bs, acc);
    const int tid = threadIdx.x, lane = tid & 63, w = tid >> 6;
    const int quad = lane >> 4, l15 = lane & 15;
    const int wm = (w >> 1) * 64, wn = (w & 1) * 64;
    const int seg = n0 >> 9;
    const float* bias = (seg == 0) ? p0 : ((seg == 1) ? p1 : p2);
    #pragma unroll
    for (int mi = 0; mi < 4; mi++)
        #pragma unroll
        for (int ni = 0; ni < 4; ni++)
            #pragma unroll
            for (int r = 0; r < 4; r++) {
                const int row = m0 + wm + mi * 16 + quad * 4 + r;
                const int col = n0 + wn + ni * 16 + l15;
                Cg[(size_t)row * Ntot + col] =
                    __float2bfloat16(acc[mi * 4 + ni][r] + bias[col & 511]);
            }
}

// ---------------- MFMA flash self-attention (strided qkv input) ----------------
__global__ __launch_bounds__(256) void self_attn_mfma(const bf16* __restrict__ q,
                                                      const bf16* __restrict__ k,
                                                      const bf16* __restrict__ v,
                                                      int ld,
                                                      bf16* __restrict__ sa) {
    const int qc = blockIdx.x, h = blockIdx.y, b = blockIdx.z;
    const int tid = threadIdx.x, lane = tid & 63, w = tid >> 6;
    const int quad = lane >> 4, l15 = lane & 15;
    __shared__ __align__(16) short Kt[64 * 72];
    __shared__ __align__(16) short VT[64 * 72];
    __shared__ __align__(16) short Ps[4][16 * 72];
    const int qrow = b * 256 + qc * 64 + w * 16 + l15;
    const short* qg = (const short*)q + (size_t)qrow * ld + h * 64;
    short8 qf0 = *(const short8*)&qg[quad * 8];
    short8 qf1 = *(const short8*)&qg[32 + quad * 8];
    floatx4 o[4] = {};
    float den[4] = {};
    for (int kt0 = 0; kt0 < 256; kt0 += 64) {
        __syncthreads();
        {
            const int row = tid >> 2, c0 = (tid & 3) * 16;
            const short* kg = (const short*)k + (size_t)(b * 256 + kt0 + row) * ld + h * 64 + c0;
            *(short8*)&Kt[row * 72 + c0]     = *(const short8*)kg;
            *(short8*)&Kt[row * 72 + c0 + 8] = *(const short8*)(kg + 8);
        }
        {
            const int key = tid & 63, dk0 = (tid >> 6) * 16;
            const short* vg = (const short*)v + (size_t)(b * 256 + kt0 + key) * ld + h * 64 + dk0;
            short8 v0 = *(const short8*)vg;
            short8 v1 = *(const short8*)(vg + 8);
            #pragma unroll
            for (int i = 0; i < 8; i++) VT[(dk0 + i) * 72 + key] = v0[i];
            #pragma unroll
            for (int i = 0; i < 8; i++) VT[(dk0 + 8 + i) * 72 + key] = v1[i];
        }
        __syncthreads();
        floatx4 sacc[4] = {};
        #pragma unroll
        for (int ni = 0; ni < 4; ni++) {
            short8 b0 = *(const short8*)&Kt[(ni * 16 + l15) * 72 + quad * 8];
            short8 b1 = *(const short8*)&Kt[(ni * 16 + l15) * 72 + 32 + quad * 8];
            sacc[ni] = __builtin_amdgcn_mfma_f32_16x16x32_bf16(qf0, b0, sacc[ni], 0, 0, 0);
            sacc[ni] = __builtin_amdgcn_mfma_f32_16x16x32_bf16(qf1, b1, sacc[ni], 0, 0, 0);
        }
        #pragma unroll
        for (int ni = 0; ni < 4; ni++)
            #pragma unroll
            for (int r = 0; r < 4; r++) {
                const float e = __expf(sacc[ni][r] * SCALE);
                den[r] += e;
                Ps[w][(quad * 4 + r) * 72 + ni * 16 + l15] = f2s(e);
            }
        #pragma unroll
        for (int kc = 0; kc < 2; kc++) {
            short8 af = *(const short8*)&Ps[w][l15 * 72 + kc * 32 + quad * 8];
            #pragma unroll
            for (int ni = 0; ni < 4; ni++) {
                short8 bv = *(const short8*)&VT[(ni * 16 + l15) * 72 + kc * 32 + quad * 8];
                o[ni] = __builtin_amdgcn_mfma_f32_16x16x32_bf16(af, bv, o[ni], 0, 0, 0);
            }
        }
    }
    #pragma unroll
    for (int off = 1; off < 16; off <<= 1)
        #pragma unroll
        for (int r = 0; r < 4; r++) den[r] += __shfl_xor(den[r], off, 64);
    float inv[4];
    #pragma unroll
    for (int r = 0; r < 4; r++) inv[r] = 1.f / den[r];
    const int qo = b * 256 + qc * 64 + w * 16 + quad * 4;
    #pragma unroll
    for (int ni = 0; ni < 4; ni++)
        #pragma unroll
        for (int r = 0; r < 4; r++)
            sa[(size_t)(qo + r) * D_MODEL + h * 64 + ni * 16 + l15] =
                __float2bfloat16(o[ni][r] * inv[r]);
}

// -------- cross attention v5: v3 algorithm, 512 threads (8 waves/CU) ---------
__global__ __launch_bounds__(512) void cross_attn5(const bf16* __restrict__ kv,
                                                   const bf16* __restrict__ cq,
                                                   const int* __restrict__ sidx,
                                                   float* __restrict__ res,
                                                   float* __restrict__ out_attn) {
    const int s = blockIdx.x, b = blockIdx.y, t = threadIdx.x;
    __shared__ int wrange[2];
    __shared__ __align__(16) short Ks[32 * 576];
    __shared__ __align__(16) short Vs[32 * 576];
    __shared__ __align__(16) short qs[32 * 576];
    __shared__ float att[32 * 256];
    if (t == 0) { wrange[0] = 256; wrange[1] = 0; }
    __syncthreads();
    const int* sb = sidx + b * 256;
    if (t < 256) {
        const int sv = sb[t];
        if (sv == s) {
            if (t == 0 || sb[t - 1] != s) wrange[0] = t;
            if (t == 255 || sb[t + 1] != s) wrange[1] = t + 1;
        }
    }
    {
        const int tt = t & 255;
        const int v = tt >> 3, hh = tt & 7;
        const short* kg = (const short*)kv + ((size_t)((b * 16 + s) * 32 + v)) * 1024 + hh * 64;
        if (t < 256) {
            short* kd = &Ks[v * 576 + hh * 72];
            #pragma unroll
            for (int c = 0; c < 8; c++)
                *(short8*)&kd[c * 8] = *(const short8*)&kg[c * 8];
        } else {
            const short* vg = kg + 512;
            short* vd = &Vs[v * 576 + hh * 72];
            #pragma unroll
            for (int c = 0; c < 8; c++)
                *(short8*)&vd[c * 8] = *(const short8*)&vg[c * 8];
        }
    }
    __syncthreads();
    const int w0 = wrange[0], w1 = wrange[1];
    const int half = t >> 8, tt = t & 255;
    const int h2 = tt >> 5, dp = tt & 31;
    const short* cqg = (const short*)cq;
    for (int wc = w0; wc < w1; wc += 32) {
        const int len = (w1 - wc < 32) ? (w1 - wc) : 32;
        for (int i = t; i < len * 64; i += 512) {
            const int e = i * 8;
            const int row = e >> 9, col = e & 511;
            *(short8*)&qs[row * 576 + (col >> 6) * 72 + (col & 63)] =
                *(const short8*)&cqg[((size_t)(b * 256 + wc + row)) * 512 + col];
        }
        __syncthreads();
        for (int i = t; i < len * 256; i += 512) {
            const int wl = i >> 8, r = i & 255, v = r >> 3, h = r & 7;
            const short* qp = &qs[wl * 576 + h * 72];
            const short* kp = &Ks[v * 576 + h * 72];
            float dot = 0.f;
            #pragma unroll
            for (int c = 0; c < 8; c++) {
                short8 q8 = *(const short8*)&qp[c * 8];
                short8 k8 = *(const short8*)&kp[c * 8];
                dot += s2f(q8[0]) * s2f(k8[0]) + s2f(q8[1]) * s2f(k8[1])
                     + s2f(q8[2]) * s2f(k8[2]) + s2f(q8[3]) * s2f(k8[3])
                     + s2f(q8[4]) * s2f(k8[4]) + s2f(q8[5]) * s2f(k8[5])
                     + s2f(q8[6]) * s2f(k8[6]) + s2f(q8[7]) * s2f(k8[7]);
            }
            att[wl * 256 + r] = 1.f / (1.f + __expf(-dot * SCALE));
        }
        __syncthreads();
        for (int wl = half; wl < len; wl += 2) {
            float r0 = 0.f, r1 = 0.f;
            #pragma unroll
            for (int vv = 0; vv < 32; ++vv) {
                const float av = att[wl * 256 + vv * 8 + h2];
                const int pv = *(const int*)&Vs[vv * 576 + h2 * 72 + dp * 2];
                r0 += av * s2f((short)(pv & 0xffff));
                r1 += av * s2f((short)(pv >> 16));
            }
            *(float2*)&res[((size_t)(b * 256 + wc + wl)) * 512 + h2 * 64 + dp * 2] =
                make_float2(r0, r1);
        }
        if (t < 32) {
            for (int wl = 0; wl < len; wl++) {
                float m = 0.f;
                #pragma unroll
                for (int j = 0; j < 8; j++) m += att[wl * 256 + t * 8 + j];
                out_attn[((size_t)(b * 256 + wc + wl)) * 32 + t] = m * 0.125f;
            }
        }
        __syncthreads();
    }
}

// ---------------------------------------------------------------------------
extern "C" void kernel_launch(void* const* d_in, const int* in_sizes, int n_in,
                              void* d_out, int out_size, void* d_ws, size_t ws_size,
                              hipStream_t stream) {
    const int B = 16, S = 16;
    const int M1 = 4096, M2 = 8192;

    const float* text = (const float*)d_in[0];
    const float* av   = (const float*)d_in[1];
    const int* sidx   = (const int*)d_in[3];
    const float* ln_res1_g = (const float*)d_in[4];
    const float* ln_res1_b = (const float*)d_in[5];
    const float* sa_wq = (const float*)d_in[6];
    const float* sa_bq = (const float*)d_in[7];
    const float* sa_wk = (const float*)d_in[8];
    const float* sa_bk = (const float*)d_in[9];
    const float* sa_wv = (const float*)d_in[10];
    const float* sa_bv = (const float*)d_in[11];
    const float* sa_wo = (const float*)d_in[12];
    const float* sa_bo = (const float*)d_in[13];
    const float* ca_ln_text_g = (const float*)d_in[14];
    const float* ca_ln_text_b = (const float*)d_in[15];
    const float* ca_ln_av_g = (const float*)d_in[16];
    const float* ca_ln_av_b = (const float*)d_in[17];
    const float* ca_wq = (const float*)d_in[18];
    const float* ca_bq = (const float*)d_in[19];
    const float* ca_wk = (const float*)d_in[20];
    const float* ca_bk = (const float*)d_in[21];
    const float* ca_wv = (const float*)d_in[22];
    const float* ca_bv = (const float*)d_in[23];
    const float* ln1_g = (const float*)d_in[24];
    const float* ln1_b = (const float*)d_in[25];
    const float* ln2_g = (const float*)d_in[26];
    const float* ln2_b = (const float*)d_in[27];
    const float* ln_res2_g = (const float*)d_in[28];
    const float* ln_res2_b = (const float*)d_in[29];
    const float* ff_w1 = (const float*)d_in[30];
    const float* ff_b1 = (const float*)d_in[31];
    const float* ff_w2 = (const float*)d_in[32];
    const float* ff_b2 = (const float*)d_in[33];

    // ---- workspace arena (byte offsets; all unique, 94 MB total) ----
    char* wsb = (char*)d_ws;
    const size_t MBy = 1024 * 1024;
    bf16*  WT    = (bf16*)(wsb);               // 0-6 weightsT
    bf16*  xln   = (bf16*)(wsb + 6 * MBy);     // 6-10 [4096][512]
    bf16*  qkv   = (bf16*)(wsb + 10 * MBy);    // 10-22 [4096][1536]
    bf16*  sab   = (bf16*)(wsb + 22 * MBy);    // 22-26
    float* text1 = (float*)(wsb + 26 * MBy);   // 26-34 f32
    bf16*  tn    = (bf16*)(wsb + 34 * MBy);    // 34-38
    bf16*  an    = (bf16*)(wsb + 38 * MBy);    // 38-46 [8192][512]
    bf16*  cqb   = (bf16*)(wsb + 46 * MBy);    // 46-50 [4096][512]
    bf16*  kvb   = (bf16*)(wsb + 50 * MBy);    // 50-66 [8192][1024]
    float* res   = (float*)(wsb + 66 * MBy);   // 66-74 f32
    float* text2 = (float*)(wsb + 74 * MBy);   // 74-82 f32
    bf16*  y     = (bf16*)(wsb + 82 * MBy);    // 82-86
    bf16*  h1    = (bf16*)(wsb + 86 * MBy);    // 86-94 [4096][1024]

    bf16* wqT  = WT;                 // wq|wk|wv contiguous => [1536][512]
    bf16* cwqT = WT + 1048576;
    bf16* cwkT = WT + 1310720;       // cwk|cwv contiguous => [1024][512]
    bf16* woT  = WT + 786432;
    bf16* f1T  = WT + 1835008;       // [1024][512]
    bf16* f2T  = WT + 2359296;       // [512][1024]

    float* out_text = (float*)d_out;
    float* out_attn = (float*)d_out + (size_t)M1 * D_MODEL;

    // ---- transpose plan (64x64 tiles) ----
    TransArgs ta;
    const float* srcs[9] = {sa_wq, sa_wk, sa_wv, sa_wo, ca_wq, ca_wk, ca_wv, ff_w1, ff_w2};
    bf16* dsts[9] = {wqT, WT + 262144, WT + 524288, woT, cwqT, cwkT, WT + 1572864, f1T, f2T};
    const int Ks_[9] = {512, 512, 512, 512, 512, 512, 512, 512, 1024};
    const int Ns_[9] = {512, 512, 512, 512, 512, 512, 512, 1024, 512};
    int cum = 0;
    for (int i = 0; i < 9; i++) {
        ta.src[i] = srcs[i]; ta.dst[i] = dsts[i]; ta.K[i] = Ks_[i]; ta.N[i] = Ns_[i];
        ta.start[i] = cum;
        cum += (Ks_[i] >> 6) * (Ns_[i] >> 6);
    }
    ta.start[9] = cum;   // 704

    const dim3 blk256(256);
    const dim3 gD(8, 32);       // N=512, BN=64 -> 256 blocks
    const dim3 gF1(8, 32);      // N=1024, BN=128 -> 256 blocks

    // 1. prologue: transpose 64x64 | LN(text) x1024 | LN(av) x2048
    prologue_kernel<<<cum + 1024 + 2048, blk256, 0, stream>>>(ta, cum,
                                                              text, ln_res1_g, ln_res1_b, xln,
                                                              av, ca_ln_av_g, ca_ln_av_b, an);
    // 2. QKV | KV fused projections (one dispatch, 128x128 tiles, 896 blocks)
    gemm_qkv_kv<<<896, blk256, 0, stream>>>(xln, wqT, sa_bq, sa_bk, sa_bv, qkv,
                                            an, cwkT, ca_bk, ca_bv, kvb);
    // 3. MFMA flash self attention (strided qkv) -> sab bf16
    self_attn_mfma<<<dim3(4, NUM_HEAD, B), blk256, 0, stream>>>(qkv, qkv + 512, qkv + 1024, 1536, sab);
    // 4. text1 = text + sab @ woT + bo (f32)
    gemm128<64, 1, false, false><<<gD, blk256, 0, stream>>>(sab, woT, sa_bo, text, text1, M1, D_MODEL, D_MODEL);
    // 5. tn = LN(text1) -> bf16 (wave-parallel, 1024 blocks)
    ln_kernel<<<1024, blk256, 0, stream>>>(text1, ca_ln_text_g, ca_ln_text_b, tn);
    // 6. cq projection -> bf16
    gemm128<64, 0, false, true><<<gD, blk256, 0, stream>>>(tn, cwqT, ca_bq, nullptr, cqb, M1, D_MODEL, D_MODEL);
    // 7. cross attention v5 (bf16 q, 512 threads; fuses att-mean -> out_attn)
    cross_attn5<<<dim3(S, B), dim3(512), 0, stream>>>(kvb, cqb, sidx, res, out_attn);
    // 8. fused: text2 = LN(text1)+LN(res); y = LN(text2) -> bf16 (1024 blocks)
    ln2_add_ln_kernel<<<1024, blk256, 0, stream>>>(text1, res, ln1_g, ln1_b, ln2_g, ln2_b,
                                                   ln_res2_g, ln_res2_b, text2, y);
    // 9. h1 = relu(y @ f1T + b1) -> bf16 (128x128 tiles)
    gemm128<128, 0, true, true><<<gF1, blk256, 0, stream>>>(y, f1T, ff_b1, nullptr, h1, M1, 1024, D_MODEL);
    // 10. out = text2 + h1 @ f2T + b2 -> f32 d_out
    gemm128<64, 1, false, false><<<gD, blk256, 0, stream>>>(h1, f2T, ff_b2, text2, out_text, M1, D_MODEL, 1024);
}